// Round 1
// baseline (235.696 us; speedup 1.0000x reference)
//
#include <hip/hip_runtime.h>

// Problem constants (fixed by reference)
#define CC 32
#define HH 256
#define WW 512
#define NN 4
#define MAXD 48

// Tiling
#define WT 128            // w-chunk per block
#define RW (WT + MAXD)    // 176 r columns staged (w0-48 .. w0+127)
#define DTILE 12          // d per thread (d0 = 12*dg, multiple of 4 -> aligned r window)
#define WTILE 4           // w per thread (wb = 4*wg, multiple of 4 -> aligned float4)
// block = 128 threads = 32 w-groups x 4 d-groups; LDS 38.9 KB -> 4 blocks/CU

__global__ __launch_bounds__(128, 2)
void cost_volume_kernel(const float* __restrict__ L,
                        const float* __restrict__ R,
                        float* __restrict__ out)
{
    __shared__ float l_s[CC][WT];   // 16 KB
    __shared__ float r_s[CC][RW];   // 22 KB

    const int t  = threadIdx.x;          // 0..127
    const int w0 = blockIdx.x * WT;      // 0,128,256,384
    const int h  = blockIdx.y;
    const int n  = blockIdx.z;

    const size_t chw  = (size_t)HH * WW;                 // channel stride
    const size_t rowL = ((size_t)n * CC * HH + h) * WW;  // (n, c=0, h, 0)

    // ---- stage l: 32 rows x 128 floats = 1024 float4, 8 per thread, coalesced
    #pragma unroll
    for (int k = 0; k < 8; ++k) {
        int idx = t + 128 * k;           // 0..1023
        int c   = idx >> 5;              // 32 float4 per row
        int j4  = idx & 31;
        float4 v = *(const float4*)(L + rowL + (size_t)c * chw + w0 + 4 * j4);
        *(float4*)&l_s[c][4 * j4] = v;
    }
    // ---- stage r: 32 rows x 176 floats = 1408 float4, 11 per thread
    #pragma unroll
    for (int k = 0; k < 11; ++k) {
        int idx = t + 128 * k;           // 0..1407
        int c   = idx / 44;              // 44 float4 per row
        int j4  = idx - c * 44;
        int g   = w0 - MAXD + 4 * j4;    // global w of first lane of this float4
        float4 v = make_float4(0.f, 0.f, 0.f, 0.f);
        if (g >= 0)                      // w<0 -> zeros (implements zero pad / w<d)
            v = *(const float4*)(R + rowL + (size_t)c * chw + g);
        *(float4*)&r_s[c][4 * j4] = v;
    }
    __syncthreads();

    const int wg = t & 31;
    const int dg = t >> 5;               // 0..3
    const int wb = wg * WTILE;           // local w base, multiple of 4
    const int d0 = dg * DTILE;           // 0,12,24,36  (multiple of 4)
    // r_s column for (local w, d) is  lw + 48 - d.
    // needed window: [wb+37-d0, wb+51-d0]; aligned superset starts at:
    const int jA = wb + 36 - d0;         // multiple of 4, 0..160, jA+15 <= 175

    float acc[DTILE][WTILE];
    #pragma unroll
    for (int k = 0; k < DTILE; ++k)
        #pragma unroll
        for (int i = 0; i < WTILE; ++i)
            acc[k][i] = 0.f;

    for (int c = 0; c < CC; ++c) {
        const float4 lv = *(const float4*)&l_s[c][wb];
        float rv[16];
        #pragma unroll
        for (int q = 0; q < 4; ++q)
            *(float4*)&rv[4 * q] = *(const float4*)&r_s[c][jA + 4 * q];
        const float lf[4] = {lv.x, lv.y, lv.z, lv.w};
        #pragma unroll
        for (int k = 0; k < DTILE; ++k)
            #pragma unroll
            for (int i = 0; i < WTILE; ++i)
                acc[k][i] += lf[i] * rv[12 + i - k];   // offsets 1..15, compile-time
    }

    const float inv = 1.0f / 32.0f;      // mean over C, exact pow2
    #pragma unroll
    for (int k = 0; k < DTILE; ++k) {
        const int d = d0 + k;
        float4 o = make_float4(acc[k][0] * inv, acc[k][1] * inv,
                               acc[k][2] * inv, acc[k][3] * inv);
        *(float4*)(out + (((size_t)n * MAXD + d) * HH + h) * WW + w0 + wb) = o;
    }
}

extern "C" void kernel_launch(void* const* d_in, const int* in_sizes, int n_in,
                              void* d_out, int out_size, void* d_ws, size_t ws_size,
                              hipStream_t stream) {
    const float* L = (const float*)d_in[0];
    const float* R = (const float*)d_in[1];
    float* out = (float*)d_out;
    // d_in[2] (use_naive) is ignored per reference.
    dim3 grid(WW / WT, HH, NN);          // 4 x 256 x 4 = 4096 blocks
    cost_volume_kernel<<<grid, dim3(128, 1, 1), 0, stream>>>(L, R, out);
}